// Round 14
// baseline (501.050 us; speedup 1.0000x reference)
//
#include <hip/hip_runtime.h>
#include <cmath>

#define NB 512
#define NT 200
#define NIN 88
#define NH 60
#define NZ 100

typedef float f2 __attribute__((ext_vector_type(2)));
typedef _Float16 h2v __attribute__((ext_vector_type(2)));
typedef _Float16 h8v __attribute__((ext_vector_type(8)));

__device__ __forceinline__ f2 pk_fma(f2 a, f2 b, f2 c) {
    return __builtin_elementwise_fma(a, b, c);
}
__device__ __forceinline__ float dot2(h2v a, h2v b, float c) {
#if __has_builtin(__builtin_amdgcn_fdot2)
    return __builtin_amdgcn_fdot2(a, b, c, false);
#else
    return fmaf((float)a.x, (float)b.x, fmaf((float)a.y, (float)b.y, c));
#endif
}
// 8-wide f16 dot into two f32 accumulators
__device__ __forceinline__ void dot8(h8v x, h8v w, float& p, float& q) {
    p = dot2(h2v{x[0], x[1]}, h2v{w[0], w[1]}, p);
    q = dot2(h2v{x[2], x[3]}, h2v{w[2], w[3]}, q);
    p = dot2(h2v{x[4], x[5]}, h2v{w[4], w[5]}, p);
    q = dot2(h2v{x[6], x[7]}, h2v{w[6], w[7]}, q);
}
__device__ __forceinline__ float fast_tanh(float x) {
    float cx = fminf(fmaxf(x, -10.f), 10.f);
    float e  = __expf(2.f * cx);
    return (e - 1.f) * __builtin_amdgcn_rcpf(e + 1.f);
}
__device__ __forceinline__ float fast_softplus(float x) {
    return fmaxf(x, 0.f) + __logf(1.f + __expf(-fabsf(x)));
}
__device__ __forceinline__ void block_sync_lds() {
    asm volatile("s_waitcnt lgkmcnt(0)" ::: "memory");
    __builtin_amdgcn_s_barrier();
    asm volatile("" ::: "memory");
}

// ---------------------------------------------------------------------------
// Kernel 1: pre[b][t][h] = x_rev[b][t].W_ih[h] + b_ih[h] + b_hh[h]
// ---------------------------------------------------------------------------
#define TCHUNKS 5
#define TCL (NT / TCHUNKS)   // 40

__global__ __launch_bounds__(128, 1)
void pre_kernel(const float* __restrict__ xrev, const float* __restrict__ W_ih,
                const float* __restrict__ b_ih, const float* __restrict__ b_hh,
                float* __restrict__ pre)
{
    __shared__ __align__(16) float xw[2][NIN];

    const int b    = blockIdx.x;
    const int tc   = blockIdx.y;
    const int wv   = threadIdx.x >> 6;
    const int lane = threadIdx.x & 63;

    f2 wih2[44];
    float bias = 0.f;
    if (lane < NH) {
        const float4* p = reinterpret_cast<const float4*>(W_ih + lane * NIN);
#pragma unroll
        for (int k = 0; k < 22; ++k) {
            float4 v = p[k];
            wih2[2*k]   = f2{v.x, v.y};
            wih2[2*k+1] = f2{v.z, v.w};
        }
        bias = b_ih[lane] + b_hh[lane];
    } else {
#pragma unroll
        for (int k = 0; k < 44; ++k) wih2[k] = f2{0.f, 0.f};
    }

    const float* xb = xrev + ((size_t)b * NT + (size_t)tc * TCL) * NIN;
    float* pb = pre + ((size_t)b * NT + (size_t)tc * TCL) * NH;

    float xa = xb[(size_t)wv * NIN + lane];
    float xc = (lane < NIN - 64) ? xb[(size_t)wv * NIN + 64 + lane] : 0.f;

    for (int k = 0; k < TCL / 2; ++k) {
        const int t = wv + 2 * k;
        xw[wv][lane] = xa;
        if (lane < NIN - 64) xw[wv][64 + lane] = xc;
        const int tn = t + 2;
        if (tn < TCL) {
            xa = xb[(size_t)tn * NIN + lane];
            xc = (lane < NIN - 64) ? xb[(size_t)tn * NIN + 64 + lane] : 0.f;
        }
        const float4* x4 = reinterpret_cast<const float4*>(xw[wv]);
        f2 a0 = f2{bias, 0.f}, a1 = f2{0.f, 0.f};
#pragma unroll
        for (int q = 0; q < 22; ++q) {
            float4 v = x4[q];
            a0 = pk_fma(f2{v.x, v.y}, wih2[2*q],   a0);
            a1 = pk_fma(f2{v.z, v.w}, wih2[2*q+1], a1);
        }
        if (lane < NH) pb[(size_t)t * NH + lane] = (a0.x + a1.x) + (a0.y + a1.y);
    }
}

// ---------------------------------------------------------------------------
// Kernel 2: fused encoder — ONE WAVE, TWO SEQUENCES, ZERO BARRIERS, with
// phase-B out-weights streamed from LDS (r13) so dual-seq register demand
// (~130) fits the grant (r11's dual attempt spilled at ~240 demand).
// The two chains' independent work fills each other's dependency-stall
// slots (r13 PMC: 53% stall at 1 seq/wave). Streamed weight chunks are
// loaded ONCE and reused for both sequences' dots.
// 256 blocks x 64 thr = 1 wave/CU; LDS ~90 KB (1 block/CU).
// ---------------------------------------------------------------------------
#define WOUT_BYTES (8 * 64 * 80)   // 40960

__global__ __launch_bounds__(64, 1)
void fused2s(const int*   __restrict__ seqlen, // [B]
             const float* __restrict__ eps,    // [T][B][Z]
             const float* __restrict__ W_hh,   // [H][H]
             const float* __restrict__ h0,
             const float* __restrict__ zq0,
             const float* __restrict__ W_zh,   // [H][Z]
             const float* __restrict__ b_zh,
             const float* __restrict__ W_hl,   // [Z][H]
             const float* __restrict__ b_hl,
             const float* __restrict__ W_hs,   // [Z][H]
             const float* __restrict__ b_hs,
             const float* __restrict__ pre,    // [B][T][H] (ws)
             float* __restrict__ out)          // 3 x [B][T][Z]
{
    __shared__ __align__(16) _Float16 h_rev_h[2][NT][NH];  // 48000 B
    __shared__ __align__(16) float    hbufF[2][64];
    __shared__ __align__(16) _Float16 zbh[2][112];
    __shared__ __align__(16) _Float16 hch[2][64];
    __shared__ __align__(16) char     wout[WOUT_BYTES];    // 40960 B

    const int lane = threadIdx.x;            // one wave
    const int b0   = blockIdx.x * 2;
    const int b1   = b0 + 1;
    const int sl0  = seqlen[b0];
    const int sl1  = seqlen[b1];

    // zero padded tails (both seqs)
    {
        const int tail = (NT - sl0) * NH;
        _Float16* p = &h_rev_h[0][sl0][0];
        for (int i = lane; i < tail; i += 64) p[i] = (_Float16)0;
    }
    {
        const int tail = (NT - sl1) * NH;
        _Float16* p = &h_rev_h[1][sl1][0];
        for (int i = lane; i < tail; i += 64) p[i] = (_Float16)0;
    }
    if (lane < 12) { zbh[0][100 + lane] = (_Float16)0; zbh[1][100 + lane] = (_Float16)0; }
    if (lane >= NH) { hch[0][lane] = (_Float16)0; hch[1][lane] = (_Float16)0; }

    const bool oln = (lane < 50);
    const int  o1  = lane;
    const int  o2  = lane + 50;
    float e1_0 = 0.f, e2_0 = 0.f, e1_1 = 0.f, e2_1 = 0.f;
    if (oln) {
        float zA = zq0[o1], zB = zq0[o2];
        zbh[0][o1] = (_Float16)zA; zbh[0][o2] = (_Float16)zB;
        zbh[1][o1] = (_Float16)zA; zbh[1][o2] = (_Float16)zB;
        e1_0 = eps[(size_t)b0 * NZ + o1];
        e2_0 = eps[(size_t)b0 * NZ + o2];
        e1_1 = eps[(size_t)b1 * NZ + o1];
        e2_1 = eps[(size_t)b1 * NZ + o2];
    }

    // ---- fill wout: 0.5-folded f16 rows; slots r=0..3 = {Whl[o1],Whs[o1],
    //      Whl[o2],Whs[o2]}; weights seq-independent -> one shared copy ----
    if (oln) {
        const float* s0 = W_hl + o1 * NH;
        const float* s1 = W_hs + o1 * NH;
        const float* s2 = W_hl + o2 * NH;
        const float* s3 = W_hs + o2 * NH;
#pragma unroll
        for (int r = 0; r < 4; ++r) {
            const float* src = (r == 0) ? s0 : (r == 1) ? s1 : (r == 2) ? s2 : s3;
#pragma unroll
            for (int k = 0; k < 8; ++k) {
                h8v h;
#pragma unroll
                for (int e = 0; e < 8; ++e) {
                    const int j = 8 * k + e;
                    h[e] = (_Float16)((j < NH) ? 0.5f * src[j] : 0.f);
                }
                *reinterpret_cast<h8v*>(wout + k*5120 + lane*80 + r*16) = h;
            }
        }
    } else {
        h8v zz;
#pragma unroll
        for (int e = 0; e < 8; ++e) zz[e] = (_Float16)0;
#pragma unroll
        for (int k = 0; k < 8; ++k) {
#pragma unroll
            for (int r = 0; r < 4; ++r)
                *reinterpret_cast<h8v*>(wout + k*5120 + lane*80 + r*16) = zz;
        }
    }

    // ---------------- Phase A: dual serial RNN (no barriers) ----------------
    {
        f2 whh2[30];
        if (lane < NH) {
            const float4* q = reinterpret_cast<const float4*>(W_hh + lane * NH);
#pragma unroll
            for (int k = 0; k < 15; ++k) {
                float4 v = q[k];
                whh2[2*k]   = f2{v.x, v.y};
                whh2[2*k+1] = f2{v.z, v.w};
            }
            float hv = h0[lane];
            hbufF[0][lane] = hv;
            hbufF[1][lane] = hv;
        } else {
#pragma unroll
            for (int k = 0; k < 30; ++k) whh2[k] = f2{0.f, 0.f};
        }

        const float* pbA = pre + (size_t)b0 * NT * NH;
        const float* pbB = pre + (size_t)b1 * NT * NH;
        const bool hl = (lane < NH);
        float p0a = hl ? pbA[0*NH + lane] : 0.f, p0b = hl ? pbB[0*NH + lane] : 0.f;
        float p1a = hl ? pbA[1*NH + lane] : 0.f, p1b = hl ? pbB[1*NH + lane] : 0.f;
        float p2a = hl ? pbA[2*NH + lane] : 0.f, p2b = hl ? pbB[2*NH + lane] : 0.f;
        float p3a = hl ? pbA[3*NH + lane] : 0.f, p3b = hl ? pbB[3*NH + lane] : 0.f;

        for (int t = 0; t < NT; ++t) {
            float pna = (t + 4 < NT && hl) ? pbA[(size_t)(t + 4) * NH + lane] : 0.f;
            float pnb = (t + 4 < NT && hl) ? pbB[(size_t)(t + 4) * NH + lane] : 0.f;
            const float4* h4a = reinterpret_cast<const float4*>(&hbufF[0][0]);
            const float4* h4b = reinterpret_cast<const float4*>(&hbufF[1][0]);
            f2 a0 = f2{p0a, 0.f}, a1 = f2{0.f, 0.f};
            f2 c0 = f2{p0b, 0.f}, c1 = f2{0.f, 0.f};
#pragma unroll
            for (int k = 0; k < 15; ++k) {
                float4 va = h4a[k];
                a0 = pk_fma(f2{va.x, va.y}, whh2[2*k],   a0);
                a1 = pk_fma(f2{va.z, va.w}, whh2[2*k+1], a1);
                float4 vb = h4b[k];
                c0 = pk_fma(f2{vb.x, vb.y}, whh2[2*k],   c0);
                c1 = pk_fma(f2{vb.z, vb.w}, whh2[2*k+1], c1);
            }
            float hnA = fmaxf((a0.x + a1.x) + (a0.y + a1.y), 0.f);
            float hnB = fmaxf((c0.x + c1.x) + (c0.y + c1.y), 0.f);
            if (hl) {
                hbufF[0][lane] = hnA;            // intra-wave in-order LDS
                hbufF[1][lane] = hnB;
                if (t < sl0) h_rev_h[0][sl0 - 1 - t][lane] = (_Float16)hnA;
                if (t < sl1) h_rev_h[1][sl1 - 1 - t][lane] = (_Float16)hnB;
            }
            p0a = p1a; p1a = p2a; p2a = p3a; p3a = pna;
            p0b = p1b; p1b = p2b; p2b = p3b; p3b = pnb;
        }
    }

    // ---- phase-B z-weights in registers (shared by both seqs) ----
    h2v wzh_h[52];
    float bz = 0.f;
    if (lane < NH) {
        const float4* q = reinterpret_cast<const float4*>(W_zh + lane * NZ);
#pragma unroll
        for (int k = 0; k < 25; ++k) {
            float4 v = q[k];
            wzh_h[2*k]   = h2v{(_Float16)v.x, (_Float16)v.y};
            wzh_h[2*k+1] = h2v{(_Float16)v.z, (_Float16)v.w};
        }
        bz = b_zh[lane];
    } else {
#pragma unroll
        for (int k = 0; k < 50; ++k) wzh_h[k] = h2v{(_Float16)0, (_Float16)0};
    }
    wzh_h[50] = h2v{(_Float16)0, (_Float16)0};
    wzh_h[51] = wzh_h[50];

    float blA = 0.f, bsA = 0.f, blB = 0.f, bsB = 0.f;
    if (oln) {
        blA = b_hl[o1]; bsA = b_hs[o1];
        blB = b_hl[o2]; bsB = b_hs[o2];
    }

    // ---------------- Phase B: dual combiner, streamed weights --------------
    float* out_z = out;
    float* out_l = out + (size_t)NB * NT * NZ;
    float* out_s = out + (size_t)2 * NB * NT * NZ;

    const char* wbase = wout + lane * 80;

    h8v pf0 = *reinterpret_cast<const h8v*>(wbase + 0);
    h8v pf1 = *reinterpret_cast<const h8v*>(wbase + 16);
    h8v pf2 = *reinterpret_cast<const h8v*>(wbase + 32);
    h8v pf3 = *reinterpret_cast<const h8v*>(wbase + 48);

    for (int t = 0; t < NT; ++t) {
        // z-dots for both chains (independent -> interleave fills stalls)
        const h8v* z80 = reinterpret_cast<const h8v*>(&zbh[0][0]);
        const h8v* z81 = reinterpret_cast<const h8v*>(&zbh[1][0]);
        float za0_0 = 0.f, za1_0 = 0.f, za2_0 = 0.f, za3_0 = 0.f;
        float za0_1 = 0.f, za1_1 = 0.f, za2_1 = 0.f, za3_1 = 0.f;
#pragma unroll
        for (int k = 0; k < 13; ++k) {
            h8v v0 = z80[k];
            za0_0 = dot2(h2v{v0[0], v0[1]}, wzh_h[4*k+0], za0_0);
            za1_0 = dot2(h2v{v0[2], v0[3]}, wzh_h[4*k+1], za1_0);
            za2_0 = dot2(h2v{v0[4], v0[5]}, wzh_h[4*k+2], za2_0);
            za3_0 = dot2(h2v{v0[6], v0[7]}, wzh_h[4*k+3], za3_0);
            h8v v1 = z81[k];
            za0_1 = dot2(h2v{v1[0], v1[1]}, wzh_h[4*k+0], za0_1);
            za1_1 = dot2(h2v{v1[2], v1[3]}, wzh_h[4*k+1], za1_1);
            za2_1 = dot2(h2v{v1[4], v1[5]}, wzh_h[4*k+2], za2_1);
            za3_1 = dot2(h2v{v1[6], v1[7]}, wzh_h[4*k+3], za3_1);
        }
        float hrow0 = (lane < NH) ? (float)h_rev_h[0][t][lane] : 0.f;
        float hrow1 = (lane < NH) ? (float)h_rev_h[1][t][lane] : 0.f;

        float e1n_0 = 0.f, e2n_0 = 0.f, e1n_1 = 0.f, e2n_1 = 0.f;
        if (oln && t + 1 < NT) {
            const float* ep0 = eps + ((size_t)(t + 1) * NB + b0) * NZ;
            const float* ep1 = eps + ((size_t)(t + 1) * NB + b1) * NZ;
            e1n_0 = ep0[o1]; e2n_0 = ep0[o2];
            e1n_1 = ep1[o1]; e2n_1 = ep1[o2];
        }

        if (lane < NH) {
            float a0 = (za0_0 + za1_0) + (za2_0 + za3_0) + bz;
            float a1 = (za0_1 + za1_1) + (za2_1 + za3_1) + bz;
            hch[0][lane] = (_Float16)(fast_tanh(a0) + hrow0);  // 0.5 in weights
            hch[1][lane] = (_Float16)(fast_tanh(a1) + hrow1);
        }

        // out-dots: stream shared weight chunks; reuse for BOTH sequences
        const h8v* hp0 = reinterpret_cast<const h8v*>(&hch[0][0]);
        const h8v* hp1 = reinterpret_cast<const h8v*>(&hch[1][0]);
        h8v c0 = pf0, c1 = pf1, c2 = pf2, c3 = pf3;
        float lA0_0 = 0.f, lA1_0 = 0.f, sA0_0 = 0.f, sA1_0 = 0.f;
        float lB0_0 = 0.f, lB1_0 = 0.f, sB0_0 = 0.f, sB1_0 = 0.f;
        float lA0_1 = 0.f, lA1_1 = 0.f, sA0_1 = 0.f, sA1_1 = 0.f;
        float lB0_1 = 0.f, lB1_1 = 0.f, sB0_1 = 0.f, sB1_1 = 0.f;
#pragma unroll
        for (int k = 0; k < 8; ++k) {
            h8v n0, n1, n2, n3;
            if (k < 7) {
                const char* nb = wbase + (k + 1) * 5120;
                n0 = *reinterpret_cast<const h8v*>(nb + 0);
                n1 = *reinterpret_cast<const h8v*>(nb + 16);
                n2 = *reinterpret_cast<const h8v*>(nb + 32);
                n3 = *reinterpret_cast<const h8v*>(nb + 48);
            }
            h8v x0 = hp0[k];
            h8v x1 = hp1[k];
            dot8(x0, c0, lA0_0, lA1_0);
            dot8(x0, c1, sA0_0, sA1_0);
            dot8(x0, c2, lB0_0, lB1_0);
            dot8(x0, c3, sB0_0, sB1_0);
            dot8(x1, c0, lA0_1, lA1_1);
            dot8(x1, c1, sA0_1, sA1_1);
            dot8(x1, c2, lB0_1, lB1_1);
            dot8(x1, c3, sB0_1, sB1_1);
            if (k < 7) { c0 = n0; c1 = n1; c2 = n2; c3 = n3; }
        }
        if (oln) {
            {
                float locA = lA0_0 + lA1_0 + blA;
                float psA  = sA0_0 + sA1_0 + bsA;
                float scA  = fast_softplus(psA);
                float zA   = locA + scA * e1_0;
                float locB = lB0_0 + lB1_0 + blB;
                float psB  = sB0_0 + sB1_0 + bsB;
                float scB  = fast_softplus(psB);
                float zB   = locB + scB * e2_0;
                size_t oi = ((size_t)b0 * NT + t) * NZ;
                out_z[oi + o1] = zA;   out_z[oi + o2] = zB;
                out_l[oi + o1] = locA; out_l[oi + o2] = locB;
                out_s[oi + o1] = scA;  out_s[oi + o2] = scB;
                zbh[0][o1] = (_Float16)zA;
                zbh[0][o2] = (_Float16)zB;
                e1_0 = e1n_0; e2_0 = e2n_0;
            }
            {
                float locA = lA0_1 + lA1_1 + blA;
                float psA  = sA0_1 + sA1_1 + bsA;
                float scA  = fast_softplus(psA);
                float zA   = locA + scA * e1_1;
                float locB = lB0_1 + lB1_1 + blB;
                float psB  = sB0_1 + sB1_1 + bsB;
                float scB  = fast_softplus(psB);
                float zB   = locB + scB * e2_1;
                size_t oi = ((size_t)b1 * NT + t) * NZ;
                out_z[oi + o1] = zA;   out_z[oi + o2] = zB;
                out_l[oi + o1] = locA; out_l[oi + o2] = locB;
                out_s[oi + o1] = scA;  out_s[oi + o2] = scB;
                zbh[1][o1] = (_Float16)zA;
                zbh[1][o2] = (_Float16)zB;
                e1_1 = e1n_1; e2_1 = e2n_1;
            }
        }
        if (t + 1 < NT) {
            pf0 = *reinterpret_cast<const h8v*>(wbase + 0);
            pf1 = *reinterpret_cast<const h8v*>(wbase + 16);
            pf2 = *reinterpret_cast<const h8v*>(wbase + 32);
            pf3 = *reinterpret_cast<const h8v*>(wbase + 48);
        }
    }
}

// ---------------------------------------------------------------------------
// Fallback (ws too small): proven monolithic kernel.
// ---------------------------------------------------------------------------
__global__ __launch_bounds__(128, 1)
void encoder_mono(const float* __restrict__ xrev, const int* __restrict__ seqlen,
                  const float* __restrict__ eps,
                  const float* __restrict__ W_ih, const float* __restrict__ W_hh,
                  const float* __restrict__ b_ih, const float* __restrict__ b_hh,
                  const float* __restrict__ h0,   const float* __restrict__ zq0,
                  const float* __restrict__ W_zh, const float* __restrict__ b_zh,
                  const float* __restrict__ W_hl, const float* __restrict__ b_hl,
                  const float* __restrict__ W_hs, const float* __restrict__ b_hs,
                  float* __restrict__ out)
{
    __shared__ __align__(16) float h_rev[NT][NH];
    __shared__ __align__(16) float xbuf[NIN];
    __shared__ __align__(16) float hbuf[NH];
    __shared__ __align__(16) float zbuf[NZ];
    __shared__ __align__(16) float hcomb[NH];

    const int b = blockIdx.x, tid = threadIdx.x;
    const int wave = tid >> 6, lane = tid & 63;
    const int sl = seqlen[b];

    for (int i = tid; i < NT * NH; i += 128) (&h_rev[0][0])[i] = 0.0f;
    __syncthreads();

    if (wave == 0) {
        float wih[NIN], whh[NH];
        float bias = 0.f;
        if (lane < NH) {
            const float4* pp = reinterpret_cast<const float4*>(W_ih + lane * NIN);
#pragma unroll
            for (int k = 0; k < NIN / 4; ++k) {
                float4 v = pp[k];
                wih[4*k+0]=v.x; wih[4*k+1]=v.y; wih[4*k+2]=v.z; wih[4*k+3]=v.w;
            }
            const float4* q = reinterpret_cast<const float4*>(W_hh + lane * NH);
#pragma unroll
            for (int k = 0; k < NH / 4; ++k) {
                float4 v = q[k];
                whh[4*k+0]=v.x; whh[4*k+1]=v.y; whh[4*k+2]=v.z; whh[4*k+3]=v.w;
            }
            bias = b_ih[lane] + b_hh[lane];
            hbuf[lane] = h0[lane];
        } else {
#pragma unroll
            for (int k = 0; k < NIN; ++k) wih[k] = 0.f;
#pragma unroll
            for (int k = 0; k < NH; ++k) whh[k] = 0.f;
        }
        const float* xb = xrev + (size_t)b * NT * NIN;
        float xa = xb[lane];
        float xc = (lane < NIN - 64) ? xb[64 + lane] : 0.f;
        for (int t = 0; t < NT; ++t) {
            xbuf[lane] = xa;
            if (lane < NIN - 64) xbuf[64 + lane] = xc;
            if (t + 1 < NT) {
                xa = xb[(size_t)(t+1)*NIN + lane];
                xc = (lane < NIN - 64) ? xb[(size_t)(t+1)*NIN + 64 + lane] : 0.f;
            }
            float a0=0.f,a1=0.f,a2=0.f,a3=0.f;
            const float4* x4 = reinterpret_cast<const float4*>(xbuf);
#pragma unroll
            for (int k = 0; k < NIN / 4; ++k) {
                float4 v = x4[k];
                a0 += v.x*wih[4*k+0]; a1 += v.y*wih[4*k+1];
                a2 += v.z*wih[4*k+2]; a3 += v.w*wih[4*k+3];
            }
            const float4* h4 = reinterpret_cast<const float4*>(hbuf);
#pragma unroll
            for (int k = 0; k < NH / 4; ++k) {
                float4 v = h4[k];
                a0 += v.x*whh[4*k+0]; a1 += v.y*whh[4*k+1];
                a2 += v.z*whh[4*k+2]; a3 += v.w*whh[4*k+3];
            }
            float hn = fmaxf((a0+a1)+(a2+a3)+bias, 0.f);
            if (lane < NH) {
                hbuf[lane] = hn;
                if (t < sl) h_rev[sl-1-t][lane] = hn;
            }
        }
    }
    __syncthreads();

    const int o = 50 * wave + lane;
    float wzr[NZ]; float bz = 0.f;
    if (wave == 0 && lane < NH) {
        const float4* pp = reinterpret_cast<const float4*>(W_zh + lane * NZ);
#pragma unroll
        for (int k = 0; k < NZ / 4; ++k) {
            float4 v = pp[k];
            wzr[4*k+0]=v.x; wzr[4*k+1]=v.y; wzr[4*k+2]=v.z; wzr[4*k+3]=v.w;
        }
        bz = b_zh[lane];
    } else {
#pragma unroll
        for (int k = 0; k < NZ; ++k) wzr[k] = 0.f;
    }
    float wl[NH], ws_[NH]; float bl = 0.f, bs = 0.f;
    if (lane < 50) {
        const float4* pp = reinterpret_cast<const float4*>(W_hl + o * NH);
        const float4* q  = reinterpret_cast<const float4*>(W_hs + o * NH);
#pragma unroll
        for (int k = 0; k < NH / 4; ++k) {
            float4 v = pp[k];
            wl[4*k+0]=v.x; wl[4*k+1]=v.y; wl[4*k+2]=v.z; wl[4*k+3]=v.w;
            float4 u = q[k];
            ws_[4*k+0]=u.x; ws_[4*k+1]=u.y; ws_[4*k+2]=u.z; ws_[4*k+3]=u.w;
        }
        bl = b_hl[o]; bs = b_hs[o];
        zbuf[o] = zq0[o];
    } else {
#pragma unroll
        for (int k = 0; k < NH; ++k) { wl[k]=0.f; ws_[k]=0.f; }
    }
    __syncthreads();

    float* out_z = out;
    float* out_l = out + (size_t)NB * NT * NZ;
    float* out_s = out + (size_t)2 * NB * NT * NZ;
    const float* epsb = eps + (size_t)b * NZ;
    float e_cur = (lane < 50) ? epsb[o] : 0.f;

    for (int t = 0; t < NT; ++t) {
        if (wave == 0) {
            float a0=0.f,a1=0.f,a2=0.f,a3=0.f;
            const float4* z4 = reinterpret_cast<const float4*>(zbuf);
#pragma unroll
            for (int k = 0; k < NZ / 4; ++k) {
                float4 v = z4[k];
                a0 += v.x*wzr[4*k+0]; a1 += v.y*wzr[4*k+1];
                a2 += v.z*wzr[4*k+2]; a3 += v.w*wzr[4*k+3];
            }
            if (lane < NH) {
                float a = (a0+a1)+(a2+a3)+bz;
                hcomb[lane] = 0.5f * (fast_tanh(a) + h_rev[t][lane]);
            }
        }
        block_sync_lds();
        float e_nxt = 0.f;
        if (t + 1 < NT && lane < 50) e_nxt = epsb[(size_t)(t+1)*NB*NZ + o];
        if (lane < 50) {
            float c0=0.f,c1=0.f,c2=0.f,c3=0.f, d0=0.f,d1=0.f,d2=0.f,d3=0.f;
            const float4* h4 = reinterpret_cast<const float4*>(hcomb);
#pragma unroll
            for (int k = 0; k < NH / 4; ++k) {
                float4 v = h4[k];
                c0 += v.x*wl[4*k+0];  c1 += v.y*wl[4*k+1];
                c2 += v.z*wl[4*k+2];  c3 += v.w*wl[4*k+3];
                d0 += v.x*ws_[4*k+0]; d1 += v.y*ws_[4*k+1];
                d2 += v.z*ws_[4*k+2]; d3 += v.w*ws_[4*k+3];
            }
            float loc = (c0+c1)+(c2+c3)+bl;
            float ps  = (d0+d1)+(d2+d3)+bs;
            float sc  = fast_softplus(ps);
            float zv  = loc + sc * e_cur;
            size_t oi = ((size_t)b * NT + t) * NZ + o;
            out_z[oi]=zv; out_l[oi]=loc; out_s[oi]=sc;
            zbuf[o]=zv;
        }
        e_cur = e_nxt;
        block_sync_lds();
    }
}

extern "C" void kernel_launch(void* const* d_in, const int* in_sizes, int n_in,
                              void* d_out, int out_size, void* d_ws, size_t ws_size,
                              hipStream_t stream) {
    const float* xrev   = (const float*)d_in[1];
    const int*   seqlen = (const int*)  d_in[3];
    const float* eps    = (const float*)d_in[4];
    const float* W_ih   = (const float*)d_in[5];
    const float* W_hh   = (const float*)d_in[6];
    const float* b_ih   = (const float*)d_in[7];
    const float* b_hh   = (const float*)d_in[8];
    const float* h0     = (const float*)d_in[9];
    const float* zq0    = (const float*)d_in[10];
    const float* W_zh   = (const float*)d_in[11];
    const float* b_zh   = (const float*)d_in[12];
    const float* W_hl   = (const float*)d_in[13];
    const float* b_hl   = (const float*)d_in[14];
    const float* W_hs   = (const float*)d_in[15];
    const float* b_hs   = (const float*)d_in[16];
    float* out = (float*)d_out;

    const size_t pre_bytes = (size_t)NB * NT * NH * sizeof(float);
    if (ws_size >= pre_bytes) {
        float* pre = (float*)d_ws;
        pre_kernel<<<dim3(NB, TCHUNKS), 128, 0, stream>>>(xrev, W_ih, b_ih, b_hh, pre);
        fused2s<<<NB / 2, 64, 0, stream>>>(seqlen, eps, W_hh, h0, zq0,
                                           W_zh, b_zh, W_hl, b_hl, W_hs, b_hs,
                                           pre, out);
    } else {
        encoder_mono<<<NB, 128, 0, stream>>>(xrev, seqlen, eps,
                                             W_ih, W_hh, b_ih, b_hh, h0, zq0,
                                             W_zh, b_zh, W_hl, b_hl, W_hs, b_hs,
                                             out);
    }
}

// Round 15
// 254.458 us; speedup vs baseline: 1.9691x; 1.9691x over previous
//
#include <hip/hip_runtime.h>
#include <cmath>

#define NB 512
#define NT 200
#define NIN 88
#define NH 60
#define NZ 100

typedef float f2 __attribute__((ext_vector_type(2)));
typedef _Float16 h2v __attribute__((ext_vector_type(2)));
typedef _Float16 h8v __attribute__((ext_vector_type(8)));

__device__ __forceinline__ f2 pk_fma(f2 a, f2 b, f2 c) {
    return __builtin_elementwise_fma(a, b, c);
}
__device__ __forceinline__ float dot2(h2v a, h2v b, float c) {
#if __has_builtin(__builtin_amdgcn_fdot2)
    return __builtin_amdgcn_fdot2(a, b, c, false);
#else
    return fmaf((float)a.x, (float)b.x, fmaf((float)a.y, (float)b.y, c));
#endif
}
// 8-wide f16 dot into two f32 accumulators
__device__ __forceinline__ void dot8(h8v x, h8v w, float& p, float& q) {
    p = dot2(h2v{x[0], x[1]}, h2v{w[0], w[1]}, p);
    q = dot2(h2v{x[2], x[3]}, h2v{w[2], w[3]}, q);
    p = dot2(h2v{x[4], x[5]}, h2v{w[4], w[5]}, p);
    q = dot2(h2v{x[6], x[7]}, h2v{w[6], w[7]}, q);
}
__device__ __forceinline__ float fast_tanh(float x) {
    float cx = fminf(fmaxf(x, -10.f), 10.f);
    float e  = __expf(2.f * cx);
    return (e - 1.f) * __builtin_amdgcn_rcpf(e + 1.f);
}
__device__ __forceinline__ float fast_softplus(float x) {
    return fmaxf(x, 0.f) + __logf(1.f + __expf(-fabsf(x)));
}
__device__ __forceinline__ void block_sync_lds() {
    asm volatile("s_waitcnt lgkmcnt(0)" ::: "memory");
    __builtin_amdgcn_s_barrier();
    asm volatile("" ::: "memory");
}

// ---------------------------------------------------------------------------
// Kernel 1: pre[b][t][h] = x_rev[b][t].W_ih[h] + b_ih[h] + b_hh[h]
// ---------------------------------------------------------------------------
#define TCHUNKS 5
#define TCL (NT / TCHUNKS)   // 40

__global__ __launch_bounds__(128, 1)
void pre_kernel(const float* __restrict__ xrev, const float* __restrict__ W_ih,
                const float* __restrict__ b_ih, const float* __restrict__ b_hh,
                float* __restrict__ pre)
{
    __shared__ __align__(16) float xw[2][NIN];

    const int b    = blockIdx.x;
    const int tc   = blockIdx.y;
    const int wv   = threadIdx.x >> 6;
    const int lane = threadIdx.x & 63;

    f2 wih2[44];
    float bias = 0.f;
    if (lane < NH) {
        const float4* p = reinterpret_cast<const float4*>(W_ih + lane * NIN);
#pragma unroll
        for (int k = 0; k < 22; ++k) {
            float4 v = p[k];
            wih2[2*k]   = f2{v.x, v.y};
            wih2[2*k+1] = f2{v.z, v.w};
        }
        bias = b_ih[lane] + b_hh[lane];
    } else {
#pragma unroll
        for (int k = 0; k < 44; ++k) wih2[k] = f2{0.f, 0.f};
    }

    const float* xb = xrev + ((size_t)b * NT + (size_t)tc * TCL) * NIN;
    float* pb = pre + ((size_t)b * NT + (size_t)tc * TCL) * NH;

    float xa = xb[(size_t)wv * NIN + lane];
    float xc = (lane < NIN - 64) ? xb[(size_t)wv * NIN + 64 + lane] : 0.f;

    for (int k = 0; k < TCL / 2; ++k) {
        const int t = wv + 2 * k;
        xw[wv][lane] = xa;
        if (lane < NIN - 64) xw[wv][64 + lane] = xc;
        const int tn = t + 2;
        if (tn < TCL) {
            xa = xb[(size_t)tn * NIN + lane];
            xc = (lane < NIN - 64) ? xb[(size_t)tn * NIN + 64 + lane] : 0.f;
        }
        const float4* x4 = reinterpret_cast<const float4*>(xw[wv]);
        f2 a0 = f2{bias, 0.f}, a1 = f2{0.f, 0.f};
#pragma unroll
        for (int q = 0; q < 22; ++q) {
            float4 v = x4[q];
            a0 = pk_fma(f2{v.x, v.y}, wih2[2*q],   a0);
            a1 = pk_fma(f2{v.z, v.w}, wih2[2*q+1], a1);
        }
        if (lane < NH) pb[(size_t)t * NH + lane] = (a0.x + a1.x) + (a0.y + a1.y);
    }
}

// ---------------------------------------------------------------------------
// Kernel 2: fused encoder, one wave per sequence, zero per-step barriers,
// phase-B out-weights streamed from LDS (r13 champion). One fix vs r13:
// the chunk-0 weight registers pf0..pf3 are LOOP-INVARIANT (wout is written
// once before the loop) — the per-step reload at the loop bottom forced 4
// redundant ds_read_b128 + an lgkm wait onto every serial step because the
// compiler can't prove non-aliasing vs the zbh/hch stores. Deleted.
// ---------------------------------------------------------------------------
#define WOUT_BYTES (8 * 64 * 80)   // 40960

__global__ __launch_bounds__(128, 1)
void fused1w(const int*   __restrict__ seqlen, // [B]
             const float* __restrict__ eps,    // [T][B][Z]
             const float* __restrict__ W_hh,   // [H][H]
             const float* __restrict__ h0,
             const float* __restrict__ zq0,
             const float* __restrict__ W_zh,   // [H][Z]
             const float* __restrict__ b_zh,
             const float* __restrict__ W_hl,   // [Z][H]
             const float* __restrict__ b_hl,
             const float* __restrict__ W_hs,   // [Z][H]
             const float* __restrict__ b_hs,
             const float* __restrict__ pre,    // [B][T][H] (ws)
             float* __restrict__ out)          // 3 x [B][T][Z]
{
    __shared__ __align__(16) _Float16 h_rev_h[2][NT][NH];  // 2 x 24000 B
    __shared__ __align__(16) float    hbuf[2][64];
    __shared__ __align__(16) _Float16 zbh[2][112];
    __shared__ __align__(16) _Float16 hch[2][64];
    __shared__ __align__(16) char     wout[WOUT_BYTES];    // shared by both waves

    const int wv   = threadIdx.x >> 6;
    const int lane = threadIdx.x & 63;
    const int b    = blockIdx.x * 2 + wv;     // this wave's sequence
    const int sl   = seqlen[b];

    // zero this sequence's padded tail rows [sl, NT) (f16)
    {
        const int tail = (NT - sl) * NH;
        _Float16* base = &h_rev_h[wv][sl][0];
        for (int i = lane; i < tail; i += 64) base[i] = (_Float16)0;
    }
    if (lane < 12) zbh[wv][100 + lane] = (_Float16)0;
    if (lane >= NH) hch[wv][lane] = (_Float16)0;

    const bool oln = (lane < 50);
    const int  o1  = lane;
    const int  o2  = lane + 50;
    float e1 = 0.f, e2 = 0.f;
    if (oln) {
        zbh[wv][o1] = (_Float16)zq0[o1];
        zbh[wv][o2] = (_Float16)zq0[o2];
        e1 = eps[(size_t)b * NZ + o1];
        e2 = eps[(size_t)b * NZ + o2];
    }

    // ---- fill wout (0.5-folded f16 out-rows). Waves split by slot:
    //   wv0 writes r=0 (W_hl[o1]), r=1 (W_hs[o1]); wv1 r=2 (W_hl[o2]),
    //   r=3 (W_hs[o2]). Data is seq-independent -> one shared copy.
    {
        const int r0 = 2 * wv, r1 = 2 * wv + 1;
        if (oln) {
            const int  oo   = (wv == 0) ? o1 : o2;
            const float* s0 = W_hl + oo * NH;
            const float* s1 = W_hs + oo * NH;
#pragma unroll
            for (int r = 0; r < 2; ++r) {
                const float* src = (r == 0) ? s0 : s1;
                const int rr = (r == 0) ? r0 : r1;
                float tmp[64];
#pragma unroll
                for (int j = 0; j < NH; ++j) tmp[j] = 0.5f * src[j];
#pragma unroll
                for (int j = NH; j < 64; ++j) tmp[j] = 0.f;
#pragma unroll
                for (int k = 0; k < 8; ++k) {
                    h8v h;
#pragma unroll
                    for (int e = 0; e < 8; ++e) h[e] = (_Float16)tmp[8*k+e];
                    *reinterpret_cast<h8v*>(wout + k*5120 + lane*80 + rr*16) = h;
                }
            }
        } else {
            h8v zz;
#pragma unroll
            for (int e = 0; e < 8; ++e) zz[e] = (_Float16)0;
#pragma unroll
            for (int k = 0; k < 8; ++k) {
                *reinterpret_cast<h8v*>(wout + k*5120 + lane*80 + r0*16) = zz;
                *reinterpret_cast<h8v*>(wout + k*5120 + lane*80 + r1*16) = zz;
            }
        }
    }

    // ---------------- Phase A: serial RNN (per-wave, no barriers) -----------
    {
        f2 whh2[30];
        if (lane < NH) {
            const float4* q = reinterpret_cast<const float4*>(W_hh + lane * NH);
#pragma unroll
            for (int k = 0; k < 15; ++k) {
                float4 v = q[k];
                whh2[2*k]   = f2{v.x, v.y};
                whh2[2*k+1] = f2{v.z, v.w};
            }
            hbuf[wv][lane] = h0[lane];
        } else {
#pragma unroll
            for (int k = 0; k < 30; ++k) whh2[k] = f2{0.f, 0.f};
        }

        const float* pb = pre + (size_t)b * NT * NH;
        const bool hl = (lane < NH);
        float p0 = hl ? pb[0 * NH + lane] : 0.f;
        float p1 = hl ? pb[1 * NH + lane] : 0.f;
        float p2 = hl ? pb[2 * NH + lane] : 0.f;
        float p3 = hl ? pb[3 * NH + lane] : 0.f;
        for (int t = 0; t < NT; ++t) {
            float pn = (t + 4 < NT && hl) ? pb[(size_t)(t + 4) * NH + lane] : 0.f;
            const float4* h4 = reinterpret_cast<const float4*>(&hbuf[wv][0]);
            f2 a0 = f2{p0, 0.f}, a1 = f2{0.f, 0.f};
#pragma unroll
            for (int k = 0; k < 15; ++k) {
                float4 v = h4[k];
                a0 = pk_fma(f2{v.x, v.y}, whh2[2*k],   a0);
                a1 = pk_fma(f2{v.z, v.w}, whh2[2*k+1], a1);
            }
            float hn = fmaxf((a0.x + a1.x) + (a0.y + a1.y), 0.f);
            if (hl) {
                hbuf[wv][lane] = hn;                 // intra-wave in-order LDS
                if (t < sl) h_rev_h[wv][sl - 1 - t][lane] = (_Float16)hn;
            }
            p0 = p1; p1 = p2; p2 = p3; p3 = pn;
        }
    }

    // ---- phase-B z-weights in registers (52) ----
    h2v wzh_h[52];
    float bz = 0.f;
    if (lane < NH) {
        const float4* q = reinterpret_cast<const float4*>(W_zh + lane * NZ);
#pragma unroll
        for (int k = 0; k < 25; ++k) {
            float4 v = q[k];
            wzh_h[2*k]   = h2v{(_Float16)v.x, (_Float16)v.y};
            wzh_h[2*k+1] = h2v{(_Float16)v.z, (_Float16)v.w};
        }
        bz = b_zh[lane];
    } else {
#pragma unroll
        for (int k = 0; k < 50; ++k) wzh_h[k] = h2v{(_Float16)0, (_Float16)0};
    }
    wzh_h[50] = h2v{(_Float16)0, (_Float16)0};
    wzh_h[51] = wzh_h[50];

    float blA = 0.f, bsA = 0.f, blB = 0.f, bsB = 0.f;
    if (oln) {
        blA = b_hl[o1]; bsA = b_hs[o1];
        blB = b_hl[o2]; bsB = b_hs[o2];
    }

    block_sync_lds();   // wout complete (cross-wave read); one barrier total

    // ---------------- Phase B: combiner (streamed out-weights) --------------
    float* out_z = out;
    float* out_l = out + (size_t)NB * NT * NZ;
    float* out_s = out + (size_t)2 * NB * NT * NZ;

    const char* wbase = wout + lane * 80;

    // chunk 0 weights: LOOP-INVARIANT registers (wout never changes again)
    const h8v pf0 = *reinterpret_cast<const h8v*>(wbase + 0);
    const h8v pf1 = *reinterpret_cast<const h8v*>(wbase + 16);
    const h8v pf2 = *reinterpret_cast<const h8v*>(wbase + 32);
    const h8v pf3 = *reinterpret_cast<const h8v*>(wbase + 48);

    for (int t = 0; t < NT; ++t) {
        // z-dot over this wave's own zbh (written by same wave last step)
        const h8v* z8 = reinterpret_cast<const h8v*>(&zbh[wv][0]);
        float za0 = 0.f, za1 = 0.f, za2 = 0.f, za3 = 0.f;
#pragma unroll
        for (int k = 0; k < 13; ++k) {
            h8v v = z8[k];
            za0 = dot2(h2v{v[0], v[1]}, wzh_h[4*k+0], za0);
            za1 = dot2(h2v{v[2], v[3]}, wzh_h[4*k+1], za1);
            za2 = dot2(h2v{v[4], v[5]}, wzh_h[4*k+2], za2);
            za3 = dot2(h2v{v[6], v[7]}, wzh_h[4*k+3], za3);
        }
        float hrow = (lane < NH) ? (float)h_rev_h[wv][t][lane] : 0.f;

        // eps prefetch for next step (rides in background)
        float e1n = 0.f, e2n = 0.f;
        if (oln && t + 1 < NT) {
            const float* ep = eps + ((size_t)(t + 1) * NB + b) * NZ;
            e1n = ep[o1];
            e2n = ep[o2];
        }

        if (lane < NH) {
            float a = (za0 + za1) + (za2 + za3) + bz;
            hch[wv][lane] = (_Float16)(fast_tanh(a) + hrow);  // 0.5 in weights
        }

        // out-dots: stream weight chunks from LDS (double-buffered)
        const h8v* h8p = reinterpret_cast<const h8v*>(&hch[wv][0]);
        h8v c0 = pf0, c1 = pf1, c2 = pf2, c3 = pf3;
        float lA0 = 0.f, lA1 = 0.f, sA0 = 0.f, sA1 = 0.f;
        float lB0 = 0.f, lB1 = 0.f, sB0 = 0.f, sB1 = 0.f;
#pragma unroll
        for (int k = 0; k < 8; ++k) {
            h8v n0, n1, n2, n3;
            if (k < 7) {
                const char* nb = wbase + (k + 1) * 5120;
                n0 = *reinterpret_cast<const h8v*>(nb + 0);
                n1 = *reinterpret_cast<const h8v*>(nb + 16);
                n2 = *reinterpret_cast<const h8v*>(nb + 32);
                n3 = *reinterpret_cast<const h8v*>(nb + 48);
            }
            h8v x = h8p[k];
            dot8(x, c0, lA0, lA1);
            dot8(x, c1, sA0, sA1);
            dot8(x, c2, lB0, lB1);
            dot8(x, c3, sB0, sB1);
            if (k < 7) { c0 = n0; c1 = n1; c2 = n2; c3 = n3; }
        }
        if (oln) {
            float locA = lA0 + lA1 + blA;
            float psA  = sA0 + sA1 + bsA;
            float scA  = fast_softplus(psA);
            float zA   = locA + scA * e1;
            float locB = lB0 + lB1 + blB;
            float psB  = sB0 + sB1 + bsB;
            float scB  = fast_softplus(psB);
            float zB   = locB + scB * e2;
            size_t oi = ((size_t)b * NT + t) * NZ;
            out_z[oi + o1] = zA;   out_z[oi + o2] = zB;
            out_l[oi + o1] = locA; out_l[oi + o2] = locB;
            out_s[oi + o1] = scA;  out_s[oi + o2] = scB;
            zbh[wv][o1] = (_Float16)zA;      // feedback: intra-wave in-order
            zbh[wv][o2] = (_Float16)zB;
            e1 = e1n; e2 = e2n;
        }
        // (no chunk-0 reload here: pf0..pf3 are loop-invariant)
    }
}

// ---------------------------------------------------------------------------
// Fallback (ws too small): proven monolithic kernel.
// ---------------------------------------------------------------------------
__global__ __launch_bounds__(128, 1)
void encoder_mono(const float* __restrict__ xrev, const int* __restrict__ seqlen,
                  const float* __restrict__ eps,
                  const float* __restrict__ W_ih, const float* __restrict__ W_hh,
                  const float* __restrict__ b_ih, const float* __restrict__ b_hh,
                  const float* __restrict__ h0,   const float* __restrict__ zq0,
                  const float* __restrict__ W_zh, const float* __restrict__ b_zh,
                  const float* __restrict__ W_hl, const float* __restrict__ b_hl,
                  const float* __restrict__ W_hs, const float* __restrict__ b_hs,
                  float* __restrict__ out)
{
    __shared__ __align__(16) float h_rev[NT][NH];
    __shared__ __align__(16) float xbuf[NIN];
    __shared__ __align__(16) float hbuf[NH];
    __shared__ __align__(16) float zbuf[NZ];
    __shared__ __align__(16) float hcomb[NH];

    const int b = blockIdx.x, tid = threadIdx.x;
    const int wave = tid >> 6, lane = tid & 63;
    const int sl = seqlen[b];

    for (int i = tid; i < NT * NH; i += 128) (&h_rev[0][0])[i] = 0.0f;
    __syncthreads();

    if (wave == 0) {
        float wih[NIN], whh[NH];
        float bias = 0.f;
        if (lane < NH) {
            const float4* pp = reinterpret_cast<const float4*>(W_ih + lane * NIN);
#pragma unroll
            for (int k = 0; k < NIN / 4; ++k) {
                float4 v = pp[k];
                wih[4*k+0]=v.x; wih[4*k+1]=v.y; wih[4*k+2]=v.z; wih[4*k+3]=v.w;
            }
            const float4* q = reinterpret_cast<const float4*>(W_hh + lane * NH);
#pragma unroll
            for (int k = 0; k < NH / 4; ++k) {
                float4 v = q[k];
                whh[4*k+0]=v.x; whh[4*k+1]=v.y; whh[4*k+2]=v.z; whh[4*k+3]=v.w;
            }
            bias = b_ih[lane] + b_hh[lane];
            hbuf[lane] = h0[lane];
        } else {
#pragma unroll
            for (int k = 0; k < NIN; ++k) wih[k] = 0.f;
#pragma unroll
            for (int k = 0; k < NH; ++k) whh[k] = 0.f;
        }
        const float* xb = xrev + (size_t)b * NT * NIN;
        float xa = xb[lane];
        float xc = (lane < NIN - 64) ? xb[64 + lane] : 0.f;
        for (int t = 0; t < NT; ++t) {
            xbuf[lane] = xa;
            if (lane < NIN - 64) xbuf[64 + lane] = xc;
            if (t + 1 < NT) {
                xa = xb[(size_t)(t+1)*NIN + lane];
                xc = (lane < NIN - 64) ? xb[(size_t)(t+1)*NIN + 64 + lane] : 0.f;
            }
            float a0=0.f,a1=0.f,a2=0.f,a3=0.f;
            const float4* x4 = reinterpret_cast<const float4*>(xbuf);
#pragma unroll
            for (int k = 0; k < NIN / 4; ++k) {
                float4 v = x4[k];
                a0 += v.x*wih[4*k+0]; a1 += v.y*wih[4*k+1];
                a2 += v.z*wih[4*k+2]; a3 += v.w*wih[4*k+3];
            }
            const float4* h4 = reinterpret_cast<const float4*>(hbuf);
#pragma unroll
            for (int k = 0; k < NH / 4; ++k) {
                float4 v = h4[k];
                a0 += v.x*whh[4*k+0]; a1 += v.y*whh[4*k+1];
                a2 += v.z*whh[4*k+2]; a3 += v.w*whh[4*k+3];
            }
            float hn = fmaxf((a0+a1)+(a2+a3)+bias, 0.f);
            if (lane < NH) {
                hbuf[lane] = hn;
                if (t < sl) h_rev[sl-1-t][lane] = hn;
            }
        }
    }
    __syncthreads();

    const int o = 50 * wave + lane;
    float wzr[NZ]; float bz = 0.f;
    if (wave == 0 && lane < NH) {
        const float4* pp = reinterpret_cast<const float4*>(W_zh + lane * NZ);
#pragma unroll
        for (int k = 0; k < NZ / 4; ++k) {
            float4 v = pp[k];
            wzr[4*k+0]=v.x; wzr[4*k+1]=v.y; wzr[4*k+2]=v.z; wzr[4*k+3]=v.w;
        }
        bz = b_zh[lane];
    } else {
#pragma unroll
        for (int k = 0; k < NZ; ++k) wzr[k] = 0.f;
    }
    float wl[NH], ws_[NH]; float bl = 0.f, bs = 0.f;
    if (lane < 50) {
        const float4* pp = reinterpret_cast<const float4*>(W_hl + o * NH);
        const float4* q  = reinterpret_cast<const float4*>(W_hs + o * NH);
#pragma unroll
        for (int k = 0; k < NH / 4; ++k) {
            float4 v = pp[k];
            wl[4*k+0]=v.x; wl[4*k+1]=v.y; wl[4*k+2]=v.z; wl[4*k+3]=v.w;
            float4 u = q[k];
            ws_[4*k+0]=u.x; ws_[4*k+1]=u.y; ws_[4*k+2]=u.z; ws_[4*k+3]=u.w;
        }
        bl = b_hl[o]; bs = b_hs[o];
        zbuf[o] = zq0[o];
    } else {
#pragma unroll
        for (int k = 0; k < NH; ++k) { wl[k]=0.f; ws_[k]=0.f; }
    }
    __syncthreads();

    float* out_z = out;
    float* out_l = out + (size_t)NB * NT * NZ;
    float* out_s = out + (size_t)2 * NB * NT * NZ;
    const float* epsb = eps + (size_t)b * NZ;
    float e_cur = (lane < 50) ? epsb[o] : 0.f;

    for (int t = 0; t < NT; ++t) {
        if (wave == 0) {
            float a0=0.f,a1=0.f,a2=0.f,a3=0.f;
            const float4* z4 = reinterpret_cast<const float4*>(zbuf);
#pragma unroll
            for (int k = 0; k < NZ / 4; ++k) {
                float4 v = z4[k];
                a0 += v.x*wzr[4*k+0]; a1 += v.y*wzr[4*k+1];
                a2 += v.z*wzr[4*k+2]; a3 += v.w*wzr[4*k+3];
            }
            if (lane < NH) {
                float a = (a0+a1)+(a2+a3)+bz;
                hcomb[lane] = 0.5f * (fast_tanh(a) + h_rev[t][lane]);
            }
        }
        block_sync_lds();
        float e_nxt = 0.f;
        if (t + 1 < NT && lane < 50) e_nxt = epsb[(size_t)(t+1)*NB*NZ + o];
        if (lane < 50) {
            float c0=0.f,c1=0.f,c2=0.f,c3=0.f, d0=0.f,d1=0.f,d2=0.f,d3=0.f;
            const float4* h4 = reinterpret_cast<const float4*>(hcomb);
#pragma unroll
            for (int k = 0; k < NH / 4; ++k) {
                float4 v = h4[k];
                c0 += v.x*wl[4*k+0];  c1 += v.y*wl[4*k+1];
                c2 += v.z*wl[4*k+2];  c3 += v.w*wl[4*k+3];
                d0 += v.x*ws_[4*k+0]; d1 += v.y*ws_[4*k+1];
                d2 += v.z*ws_[4*k+2]; d3 += v.w*ws_[4*k+3];
            }
            float loc = (c0+c1)+(c2+c3)+bl;
            float ps  = (d0+d1)+(d2+d3)+bs;
            float sc  = fast_softplus(ps);
            float zv  = loc + sc * e_cur;
            size_t oi = ((size_t)b * NT + t) * NZ + o;
            out_z[oi]=zv; out_l[oi]=loc; out_s[oi]=sc;
            zbuf[o]=zv;
        }
        e_cur = e_nxt;
        block_sync_lds();
    }
}

extern "C" void kernel_launch(void* const* d_in, const int* in_sizes, int n_in,
                              void* d_out, int out_size, void* d_ws, size_t ws_size,
                              hipStream_t stream) {
    const float* xrev   = (const float*)d_in[1];
    const int*   seqlen = (const int*)  d_in[3];
    const float* eps    = (const float*)d_in[4];
    const float* W_ih   = (const float*)d_in[5];
    const float* W_hh   = (const float*)d_in[6];
    const float* b_ih   = (const float*)d_in[7];
    const float* b_hh   = (const float*)d_in[8];
    const float* h0     = (const float*)d_in[9];
    const float* zq0    = (const float*)d_in[10];
    const float* W_zh   = (const float*)d_in[11];
    const float* b_zh   = (const float*)d_in[12];
    const float* W_hl   = (const float*)d_in[13];
    const float* b_hl   = (const float*)d_in[14];
    const float* W_hs   = (const float*)d_in[15];
    const float* b_hs   = (const float*)d_in[16];
    float* out = (float*)d_out;

    const size_t pre_bytes = (size_t)NB * NT * NH * sizeof(float);
    if (ws_size >= pre_bytes) {
        float* pre = (float*)d_ws;
        pre_kernel<<<dim3(NB, TCHUNKS), 128, 0, stream>>>(xrev, W_ih, b_ih, b_hh, pre);
        fused1w<<<NB / 2, 128, 0, stream>>>(seqlen, eps, W_hh, h0, zq0,
                                            W_zh, b_zh, W_hl, b_hl, W_hs, b_hs,
                                            pre, out);
    } else {
        encoder_mono<<<NB, 128, 0, stream>>>(xrev, seqlen, eps,
                                             W_ih, W_hh, b_ih, b_hh, h0, zq0,
                                             W_zh, b_zh, W_hl, b_hl, W_hs, b_hs,
                                             out);
    }
}